// Round 1
// baseline (313.007 us; speedup 1.0000x reference)
//
#include <hip/hip_runtime.h>

// Transformer layer, MI355X/gfx950.
// B=2, N=2048, C=512, H=8, D=64. Softmax over HEAD axis (faithful to ref) ->
// attention fuses per (n-tile, m-tile) with in-lane 8-way head softmax.
// bf16 MFMA for all matmuls, fp32 accumulate, fp32 residuals/output.

typedef unsigned short u16;
typedef unsigned int u32;
typedef __attribute__((ext_vector_type(4))) float f32x4;
typedef __attribute__((ext_vector_type(8))) short sv8;
typedef __attribute__((ext_vector_type(8))) __bf16 bfv8;
typedef __attribute__((ext_vector_type(8))) u16 usv8;
typedef __attribute__((ext_vector_type(4))) u16 usv4;

#define DEV static __device__ __forceinline__

DEV u16 f2bf(float f) {  // RNE fp32 -> bf16
  u32 x = __builtin_bit_cast(u32, f);
  return (u16)((x + 0x7fffu + ((x >> 16) & 1u)) >> 16);
}

DEV f32x4 mfma16(sv8 a, sv8 b, f32x4 c) {
  return __builtin_amdgcn_mfma_f32_16x16x32_bf16(
      __builtin_bit_cast(bfv8, a), __builtin_bit_cast(bfv8, b), c, 0, 0, 0);
}

DEV void gload_lds16(const void* g, void* l) {
  __builtin_amdgcn_global_load_lds(
      (const __attribute__((address_space(1))) u32*)g,
      (__attribute__((address_space(3))) u32*)l, 16, 0, 0);
}

// ---------------- weight cast: 4 fp32 weight mats -> bf16 ----------------
__global__ __launch_bounds__(256) void cast_w(
    const float* __restrict__ s0, const float* __restrict__ s1,
    const float* __restrict__ s2, const float* __restrict__ s3,
    u16* __restrict__ d0, u16* __restrict__ d1,
    u16* __restrict__ d2, u16* __restrict__ d3)
{
  int i = blockIdx.x * 256 + threadIdx.x;  // vec4 index, 786432 total
  const float* s; u16* d; int off;
  if (i < 196608)      { s = s0; d = d0; off = i; }
  else if (i < 262144) { s = s1; d = d1; off = i - 196608; }
  else if (i < 524288) { s = s2; d = d2; off = i - 262144; }
  else                 { s = s3; d = d3; off = i - 524288; }
  float4 v = ((const float4*)s)[off];
  usv4 r; r.x = f2bf(v.x); r.y = f2bf(v.y); r.z = f2bf(v.z); r.w = f2bf(v.w);
  *(usv4*)(d + (size_t)off * 4) = r;
}

// ---------------- layernorm (C=512) fp32 in -> bf16 out ----------------
__global__ __launch_bounds__(256) void ln_kernel(
    const float* __restrict__ x, const float* __restrict__ g,
    const float* __restrict__ bb, u16* __restrict__ out)
{
  const int row = (blockIdx.x << 2) + (threadIdx.x >> 6);
  const int lane = threadIdx.x & 63;
  const float4* xr = (const float4*)(x + ((size_t)row << 9));
  float4 a = xr[lane * 2], c = xr[lane * 2 + 1];
  float s  = a.x + a.y + a.z + a.w + c.x + c.y + c.z + c.w;
  float ss = a.x*a.x + a.y*a.y + a.z*a.z + a.w*a.w
           + c.x*c.x + c.y*c.y + c.z*c.z + c.w*c.w;
  #pragma unroll
  for (int off = 32; off; off >>= 1) { s += __shfl_xor(s, off); ss += __shfl_xor(ss, off); }
  const float mu = s * (1.0f / 512.0f);
  const float rstd = rsqrtf(ss * (1.0f / 512.0f) - mu * mu + 1e-6f);
  const float4* g4 = (const float4*)g;
  const float4* b4 = (const float4*)bb;
  float4 g0 = g4[lane * 2], g1 = g4[lane * 2 + 1];
  float4 b0 = b4[lane * 2], b1 = b4[lane * 2 + 1];
  usv8 rr;
  rr[0] = f2bf((a.x - mu) * rstd * g0.x + b0.x);
  rr[1] = f2bf((a.y - mu) * rstd * g0.y + b0.y);
  rr[2] = f2bf((a.z - mu) * rstd * g0.z + b0.z);
  rr[3] = f2bf((a.w - mu) * rstd * g0.w + b0.w);
  rr[4] = f2bf((c.x - mu) * rstd * g1.x + b1.x);
  rr[5] = f2bf((c.y - mu) * rstd * g1.y + b1.y);
  rr[6] = f2bf((c.z - mu) * rstd * g1.z + b1.z);
  rr[7] = f2bf((c.w - mu) * rstd * g1.w + b1.w);
  *(usv8*)(out + ((size_t)row << 9) + (lane << 3)) = rr;
}

// ---------------- GEMM: out[m][o] = sum_c A[m][c] * W[o][c] (+epilogue) ----
// EPI 0: bf16 store. EPI 1: f32 store = acc + bias + res. EPI 2: bf16 gelu(acc+bias).
template<int EPI>
__global__ __launch_bounds__(256, 2) void gemm_kernel(
    const u16* __restrict__ A, const u16* __restrict__ W,
    int K, int Nn, const float* __restrict__ bias,
    const float* __restrict__ res, void* __restrict__ outp)
{
  __shared__ u16 sA[128 * 64];
  __shared__ u16 sB[128 * 64];
  const int m0 = blockIdx.x << 7, n0 = blockIdx.y << 7;
  const int lane = threadIdx.x & 63, wave = threadIdx.x >> 6;
  const int wm = wave >> 1, wn = wave & 1;
  const int srow = lane >> 3, scol = (lane & 7) << 3;
  const int l15 = lane & 15, l4 = lane >> 4;
  f32x4 acc[4][4] = {};
  for (int kt = 0; kt < K; kt += 64) {
    #pragma unroll
    for (int i = 0; i < 4; ++i) {
      const int c = (wave << 2) + i;
      gload_lds16(A + (size_t)(m0 + (c << 3) + srow) * K + kt + scol, sA + (c << 9));
      gload_lds16(W + (size_t)(n0 + (c << 3) + srow) * K + kt + scol, sB + (c << 9));
    }
    __syncthreads();
    #pragma unroll
    for (int kk = 0; kk < 2; ++kk) {
      sv8 af[4], bfr[4];
      #pragma unroll
      for (int mi = 0; mi < 4; ++mi)
        af[mi] = *(const sv8*)(sA + (wm * 64 + mi * 16 + l15) * 64 + kk * 32 + (l4 << 3));
      #pragma unroll
      for (int ni = 0; ni < 4; ++ni)
        bfr[ni] = *(const sv8*)(sB + (wn * 64 + ni * 16 + l15) * 64 + kk * 32 + (l4 << 3));
      #pragma unroll
      for (int mi = 0; mi < 4; ++mi)
        #pragma unroll
        for (int ni = 0; ni < 4; ++ni)
          acc[mi][ni] = mfma16(af[mi], bfr[ni], acc[mi][ni]);
    }
    __syncthreads();
  }
  float bias_v[4];
  if (EPI != 0) {
    #pragma unroll
    for (int ni = 0; ni < 4; ++ni)
      bias_v[ni] = bias[n0 + wn * 64 + ni * 16 + l15];
  }
  #pragma unroll
  for (int mi = 0; mi < 4; ++mi) {
    #pragma unroll
    for (int ni = 0; ni < 4; ++ni) {
      const int gcol = n0 + wn * 64 + ni * 16 + l15;
      #pragma unroll
      for (int r = 0; r < 4; ++r) {
        const int grow = m0 + wm * 64 + mi * 16 + (l4 << 2) + r;
        float v = acc[mi][ni][r];
        if (EPI == 0) {
          ((u16*)outp)[(size_t)grow * Nn + gcol] = f2bf(v);
        } else if (EPI == 1) {
          ((float*)outp)[(size_t)grow * Nn + gcol] =
              v + bias_v[ni] + res[(size_t)grow * Nn + gcol];
        } else {
          float t = v + bias_v[ni];
          float gl = 0.5f * t * (1.0f + erff(t * 0.70710678118654752f));
          ((u16*)outp)[(size_t)grow * Nn + gcol] = f2bf(gl);
        }
      }
    }
  }
}

// ---------------- V transpose: qkv V-part -> vt[b][h][d][n] ----------------
__global__ __launch_bounds__(256) void transpose_v(
    const u16* __restrict__ qkvb, u16* __restrict__ vt)
{
  __shared__ u16 tile[64][72];
  const int bh = blockIdx.y, n0 = blockIdx.x << 6;
  const int b = bh >> 3, h = bh & 7;
  const int t = threadIdx.x;
  const int row = t >> 2, d0 = (t & 3) << 4;
  const u16* src = qkvb + (size_t)(b * 2048 + n0 + row) * 1536 + 1024 + h * 64 + d0;
  *(uint4*)&tile[row][d0]     = *(const uint4*)src;
  *(uint4*)&tile[row][d0 + 8] = *(const uint4*)(src + 8);
  __syncthreads();
  const int dr = t >> 2, nn0 = (t & 3) << 4;
  u16* dst = vt + (size_t)(bh * 64 + dr) * 2048 + n0 + nn0;
  usv8 v0, v1;
  #pragma unroll
  for (int j = 0; j < 8; ++j) v0[j] = tile[nn0 + j][dr];
  #pragma unroll
  for (int j = 0; j < 8; ++j) v1[j] = tile[nn0 + 8 + j][dr];
  *(usv8*)dst = v0;
  *(usv8*)(dst + 8) = v1;
}

// ---------------- fused attention (softmax over heads) ----------------
// grid (8 m-splits, 64 n-blocks), 256 thr. Each wave: 16 q-rows, all 8 heads.
__global__ __launch_bounds__(256, 2) void attn_kernel(
    const u16* __restrict__ qkvb, const u16* __restrict__ vt,
    float* __restrict__ accum)
{
  __shared__ u16 sK[8 * 32 * 64];   // [h][m][d], XOR-swizzled rows
  __shared__ u16 sV[8 * 64 * 40];   // [h][d][m pad->40]
  __shared__ u16 sP[4 * 16 * 40];   // per-wave P scratch [16][40]
  const int lane = threadIdx.x & 63, wave = threadIdx.x >> 6;
  const int b = blockIdx.y >> 5;
  const int n0 = (blockIdx.y & 31) << 6;
  const int m0 = blockIdx.x << 8;          // 256 m per block
  const int nrow0 = n0 + (wave << 4);
  const int l15 = lane & 15, l4 = lane >> 4;
  const float KSC = 0.125f * 1.4426950408889634f;  // scale * log2(e)
  f32x4 o_acc[8][4] = {};
  const int kh = threadIdx.x >> 5, km = threadIdx.x & 31;
  const u16* qrow = qkvb + (size_t)(b * 2048 + nrow0 + l15) * 1536;
  u16* myP = sP + wave * (16 * 40);
  for (int mt = 0; mt < 8; ++mt) {
    const int mbase = m0 + (mt << 5);
    { // stage K: thread -> one (h,m) row of 128B, swizzled
      const u16* src = qkvb + (size_t)(b * 2048 + mbase + km) * 1536 + 512 + kh * 64;
      char* dstb = (char*)sK + ((kh * 32 + km) << 7);
      const int swz = (km & 7) << 4;
      #pragma unroll
      for (int c2 = 0; c2 < 8; ++c2) {
        uint4 v = *(const uint4*)(src + (c2 << 3));
        *(uint4*)(dstb + ((c2 << 4) ^ swz)) = v;
      }
    }
    { // stage V (already transposed globally): thread -> two (h,d) rows of 64B
      const int r0 = threadIdx.x << 1;
      #pragma unroll
      for (int rr = 0; rr < 2; ++rr) {
        const int rv = r0 + rr, hh = rv >> 6, dd = rv & 63;
        const uint4* s4 = (const uint4*)(vt + (size_t)((b * 8 + hh) * 64 + dd) * 2048 + mbase);
        uint4* d4 = (uint4*)(sV + (hh * 64 + dd) * 40);
        d4[0] = s4[0]; d4[1] = s4[1]; d4[2] = s4[2]; d4[3] = s4[3];
      }
    }
    __syncthreads();
    // QK^T for all heads
    f32x4 sc[8][2];
    #pragma unroll
    for (int h = 0; h < 8; ++h) {
      sv8 qa0 = *(const sv8*)(qrow + h * 64 + (l4 << 3));
      sv8 qa1 = *(const sv8*)(qrow + h * 64 + 32 + (l4 << 3));
      #pragma unroll
      for (int ms = 0; ms < 2; ++ms) {
        const int mrow = (ms << 4) + l15;
        const int kbase = (h << 12) + (mrow << 7) + (l4 << 4);
        const int swz = (mrow & 7) << 4;
        sv8 kf0 = *(const sv8*)((const char*)sK + (kbase ^ swz));
        sv8 kf1 = *(const sv8*)((const char*)sK + ((kbase + 64) ^ swz));
        f32x4 t = {0.0f, 0.0f, 0.0f, 0.0f};
        t = mfma16(qa0, kf0, t);
        t = mfma16(qa1, kf1, t);
        sc[h][ms] = t;
      }
    }
    // softmax across the 8 heads, per (n,m) position, fully in-lane
    #pragma unroll
    for (int ms = 0; ms < 2; ++ms) {
      #pragma unroll
      for (int r = 0; r < 4; ++r) {
        float e[8]; float sum = 0.0f;
        #pragma unroll
        for (int h = 0; h < 8; ++h) { e[h] = exp2f(sc[h][ms][r] * KSC); sum += e[h]; }
        const float inv = __builtin_amdgcn_rcpf(sum);
        #pragma unroll
        for (int h = 0; h < 8; ++h) sc[h][ms][r] = e[h] * inv;
      }
    }
    // P (C-layout) -> LDS -> A-frag, then PV. Wave-private: DS in-order, no barrier.
    #pragma unroll
    for (int h = 0; h < 8; ++h) {
      #pragma unroll
      for (int ms = 0; ms < 2; ++ms)
        #pragma unroll
        for (int r = 0; r < 4; ++r)
          myP[((l4 << 2) + r) * 40 + (ms << 4) + l15] = f2bf(sc[h][ms][r]);
      sv8 pf = *(const sv8*)(myP + l15 * 40 + (l4 << 3));
      #pragma unroll
      for (int dsub = 0; dsub < 4; ++dsub) {
        sv8 vf = *(const sv8*)(sV + h * 2560 + ((dsub << 4) + l15) * 40 + (l4 << 3));
        o_acc[h][dsub] = mfma16(pf, vf, o_acc[h][dsub]);
      }
    }
    __syncthreads();
  }
  // combine m-splits
  float* obase = accum + ((size_t)(b * 2048 + nrow0) << 9);
  #pragma unroll
  for (int h = 0; h < 8; ++h)
    #pragma unroll
    for (int dsub = 0; dsub < 4; ++dsub)
      #pragma unroll
      for (int r = 0; r < 4; ++r)
        atomicAdd(obase + (size_t)((l4 << 2) + r) * 512 + h * 64 + (dsub << 4) + l15,
                  o_acc[h][dsub][r]);
}

// ---------------- fp32 -> bf16 (attention accum -> proj input) ----------------
__global__ __launch_bounds__(256) void cast8(
    const float* __restrict__ in, u16* __restrict__ out)
{
  int i = blockIdx.x * 256 + threadIdx.x;  // 262144 total, 8 elems each
  float4 a = ((const float4*)in)[i * 2], b = ((const float4*)in)[i * 2 + 1];
  usv8 r;
  r[0] = f2bf(a.x); r[1] = f2bf(a.y); r[2] = f2bf(a.z); r[3] = f2bf(a.w);
  r[4] = f2bf(b.x); r[5] = f2bf(b.y); r[6] = f2bf(b.z); r[7] = f2bf(b.w);
  *(usv8*)(out + (size_t)i * 8) = r;
}

extern "C" void kernel_launch(void* const* d_in, const int* in_sizes, int n_in,
                              void* d_out, int out_size, void* d_ws, size_t ws_size,
                              hipStream_t stream) {
  const float* x      = (const float*)d_in[0];
  const float* ln_g   = (const float*)d_in[1];
  const float* ln_b   = (const float*)d_in[2];
  const float* qkv_w  = (const float*)d_in[3];
  const float* proj_w = (const float*)d_in[4];
  const float* proj_b = (const float*)d_in[5];
  const float* fc1_w  = (const float*)d_in[6];
  const float* fc1_b  = (const float*)d_in[7];
  const float* fc2_w  = (const float*)d_in[8];
  const float* fc2_b  = (const float*)d_in[9];
  char* ws = (char*)d_ws;
  u16*   w_qkv  = (u16*)(ws + 0);         // 1536x512 bf16
  u16*   w_proj = (u16*)(ws + 1572864);   // 512x512
  u16*   w_fc1  = (u16*)(ws + 2097152);   // 2048x512
  u16*   w_fc2  = (u16*)(ws + 4194304);   // 512x2048
  u16*   xn     = (u16*)(ws + 6291456);   // 4096x512 bf16 (LN out, reused)
  u16*   qkvb   = (u16*)(ws + 10485760);  // 4096x1536 bf16
  u16*   vtb    = (u16*)(ws + 23068672);  // [2][8][64][2048] bf16
  float* accum  = (float*)(ws + 27262976);// 4096x512 f32
  u16*   attnb  = (u16*)(ws + 35651584);  // 4096x512 bf16
  float* x1     = (float*)(ws + 39845888);// 4096x512 f32
  u16*   hbuf   = (u16*)(ws + 48234496);  // 4096x2048 bf16   (end: 62MB)

  hipMemsetAsync(accum, 0, (size_t)4096 * 512 * 4, stream);
  cast_w<<<3072, 256, 0, stream>>>(qkv_w, proj_w, fc1_w, fc2_w,
                                   w_qkv, w_proj, w_fc1, w_fc2);
  ln_kernel<<<1024, 256, 0, stream>>>(x, ln_g, ln_b, xn);
  gemm_kernel<0><<<dim3(32, 12), 256, 0, stream>>>(xn, w_qkv, 512, 1536,
                                                   nullptr, nullptr, qkvb);
  transpose_v<<<dim3(32, 16), 256, 0, stream>>>(qkvb, vtb);
  attn_kernel<<<dim3(8, 64), 256, 0, stream>>>(qkvb, vtb, accum);
  cast8<<<1024, 256, 0, stream>>>(accum, attnb);
  gemm_kernel<1><<<dim3(32, 4), 256, 0, stream>>>(attnb, w_proj, 512, 512,
                                                  proj_b, x, x1);
  ln_kernel<<<1024, 256, 0, stream>>>(x1, ln_g, ln_b, xn);
  gemm_kernel<2><<<dim3(32, 16), 256, 0, stream>>>(xn, w_fc1, 512, 2048,
                                                   fc1_b, nullptr, hbuf);
  gemm_kernel<1><<<dim3(32, 4), 256, 0, stream>>>(hbuf, w_fc2, 2048, 512,
                                                  fc2_b, x1, d_out);
}

// Round 2
// 241.442 us; speedup vs baseline: 1.2964x; 1.2964x over previous
//
#include <hip/hip_runtime.h>

// Transformer layer, MI355X/gfx950.
// B=2, N=2048, C=512, H=8, D=64. Softmax over HEAD axis (faithful to ref) ->
// attention fuses per (n-tile, m-tile) with in-lane 8-way head softmax.
// bf16 MFMA for all matmuls, fp32 accumulate, fp32 residuals/output.

typedef unsigned short u16;
typedef unsigned int u32;
typedef __attribute__((ext_vector_type(4))) float f32x4;
typedef __attribute__((ext_vector_type(4))) u32 u32x4;
typedef __attribute__((ext_vector_type(8))) short sv8;
typedef __attribute__((ext_vector_type(8))) __bf16 bfv8;
typedef __attribute__((ext_vector_type(8))) u16 usv8;
typedef __attribute__((ext_vector_type(4))) u16 usv4;

#define DEV static __device__ __forceinline__

DEV u16 f2bf(float f) {  // RNE fp32 -> bf16
  u32 x = __builtin_bit_cast(u32, f);
  return (u16)((x + 0x7fffu + ((x >> 16) & 1u)) >> 16);
}

DEV f32x4 mfma16(sv8 a, sv8 b, f32x4 c) {
  return __builtin_amdgcn_mfma_f32_16x16x32_bf16(
      __builtin_bit_cast(bfv8, a), __builtin_bit_cast(bfv8, b), c, 0, 0, 0);
}

DEV void gload_lds16(const void* g, void* l) {
  __builtin_amdgcn_global_load_lds(
      (const __attribute__((address_space(1))) u32*)g,
      (__attribute__((address_space(3))) u32*)l, 16, 0, 0);
}

// ---------------- weight cast: 4 fp32 weight mats -> bf16 ----------------
__global__ __launch_bounds__(256) void cast_w(
    const float* __restrict__ s0, const float* __restrict__ s1,
    const float* __restrict__ s2, const float* __restrict__ s3,
    u16* __restrict__ d0, u16* __restrict__ d1,
    u16* __restrict__ d2, u16* __restrict__ d3)
{
  int i = blockIdx.x * 256 + threadIdx.x;  // vec4 index, 786432 total
  const float* s; u16* d; int off;
  if (i < 196608)      { s = s0; d = d0; off = i; }
  else if (i < 262144) { s = s1; d = d1; off = i - 196608; }
  else if (i < 524288) { s = s2; d = d2; off = i - 262144; }
  else                 { s = s3; d = d3; off = i - 524288; }
  float4 v = ((const float4*)s)[off];
  usv4 r; r.x = f2bf(v.x); r.y = f2bf(v.y); r.z = f2bf(v.z); r.w = f2bf(v.w);
  *(usv4*)(d + (size_t)off * 4) = r;
}

// ---------------- layernorm (C=512) fp32 in -> bf16 out ----------------
__global__ __launch_bounds__(256) void ln_kernel(
    const float* __restrict__ x, const float* __restrict__ g,
    const float* __restrict__ bb, u16* __restrict__ out)
{
  const int row = (blockIdx.x << 2) + (threadIdx.x >> 6);
  const int lane = threadIdx.x & 63;
  const float4* xr = (const float4*)(x + ((size_t)row << 9));
  float4 a = xr[lane * 2], c = xr[lane * 2 + 1];
  float s  = a.x + a.y + a.z + a.w + c.x + c.y + c.z + c.w;
  float ss = a.x*a.x + a.y*a.y + a.z*a.z + a.w*a.w
           + c.x*c.x + c.y*c.y + c.z*c.z + c.w*c.w;
  #pragma unroll
  for (int off = 32; off; off >>= 1) { s += __shfl_xor(s, off); ss += __shfl_xor(ss, off); }
  const float mu = s * (1.0f / 512.0f);
  const float rstd = rsqrtf(ss * (1.0f / 512.0f) - mu * mu + 1e-6f);
  const float4* g4 = (const float4*)g;
  const float4* b4 = (const float4*)bb;
  float4 g0 = g4[lane * 2], g1 = g4[lane * 2 + 1];
  float4 b0 = b4[lane * 2], b1 = b4[lane * 2 + 1];
  usv8 rr;
  rr[0] = f2bf((a.x - mu) * rstd * g0.x + b0.x);
  rr[1] = f2bf((a.y - mu) * rstd * g0.y + b0.y);
  rr[2] = f2bf((a.z - mu) * rstd * g0.z + b0.z);
  rr[3] = f2bf((a.w - mu) * rstd * g0.w + b0.w);
  rr[4] = f2bf((c.x - mu) * rstd * g1.x + b1.x);
  rr[5] = f2bf((c.y - mu) * rstd * g1.y + b1.y);
  rr[6] = f2bf((c.z - mu) * rstd * g1.z + b1.z);
  rr[7] = f2bf((c.w - mu) * rstd * g1.w + b1.w);
  *(usv8*)(out + ((size_t)row << 9) + (lane << 3)) = rr;
}

// ---------------- GEMM: out[m][o] = sum_c A[m][c] * W[o][c] (+epilogue) ----
// EPI 0: bf16 store. EPI 1: f32 store = acc + bias + res. EPI 2: bf16 gelu(acc+bias).
template<int EPI>
__global__ __launch_bounds__(256, 2) void gemm_kernel(
    const u16* __restrict__ A, const u16* __restrict__ W,
    int K, int Nn, const float* __restrict__ bias,
    const float* __restrict__ res, void* __restrict__ outp)
{
  __shared__ u16 sA[128 * 64];
  __shared__ u16 sB[128 * 64];
  const int m0 = blockIdx.x << 7, n0 = blockIdx.y << 7;
  const int lane = threadIdx.x & 63, wave = threadIdx.x >> 6;
  const int wm = wave >> 1, wn = wave & 1;
  const int srow = lane >> 3, scol = (lane & 7) << 3;
  const int l15 = lane & 15, l4 = lane >> 4;
  f32x4 acc[4][4] = {};
  for (int kt = 0; kt < K; kt += 64) {
    #pragma unroll
    for (int i = 0; i < 4; ++i) {
      const int c = (wave << 2) + i;
      gload_lds16(A + (size_t)(m0 + (c << 3) + srow) * K + kt + scol, sA + (c << 9));
      gload_lds16(W + (size_t)(n0 + (c << 3) + srow) * K + kt + scol, sB + (c << 9));
    }
    __syncthreads();
    #pragma unroll
    for (int kk = 0; kk < 2; ++kk) {
      sv8 af[4], bfr[4];
      #pragma unroll
      for (int mi = 0; mi < 4; ++mi)
        af[mi] = *(const sv8*)(sA + (wm * 64 + mi * 16 + l15) * 64 + kk * 32 + (l4 << 3));
      #pragma unroll
      for (int ni = 0; ni < 4; ++ni)
        bfr[ni] = *(const sv8*)(sB + (wn * 64 + ni * 16 + l15) * 64 + kk * 32 + (l4 << 3));
      #pragma unroll
      for (int mi = 0; mi < 4; ++mi)
        #pragma unroll
        for (int ni = 0; ni < 4; ++ni)
          acc[mi][ni] = mfma16(af[mi], bfr[ni], acc[mi][ni]);
    }
    __syncthreads();
  }
  float bias_v[4];
  if (EPI != 0) {
    #pragma unroll
    for (int ni = 0; ni < 4; ++ni)
      bias_v[ni] = bias[n0 + wn * 64 + ni * 16 + l15];
  }
  #pragma unroll
  for (int mi = 0; mi < 4; ++mi) {
    #pragma unroll
    for (int ni = 0; ni < 4; ++ni) {
      const int gcol = n0 + wn * 64 + ni * 16 + l15;
      #pragma unroll
      for (int r = 0; r < 4; ++r) {
        const int grow = m0 + wm * 64 + mi * 16 + (l4 << 2) + r;
        float v = acc[mi][ni][r];
        if (EPI == 0) {
          ((u16*)outp)[(size_t)grow * Nn + gcol] = f2bf(v);
        } else if (EPI == 1) {
          ((float*)outp)[(size_t)grow * Nn + gcol] =
              v + bias_v[ni] + res[(size_t)grow * Nn + gcol];
        } else {
          float t = v + bias_v[ni];
          float gl = 0.5f * t * (1.0f + erff(t * 0.70710678118654752f));
          ((u16*)outp)[(size_t)grow * Nn + gcol] = f2bf(gl);
        }
      }
    }
  }
}

// ---------------- V transpose: qkv V-part -> vt[b][h][d][n] ----------------
__global__ __launch_bounds__(256) void transpose_v(
    const u16* __restrict__ qkvb, u16* __restrict__ vt)
{
  __shared__ u16 tile[64][72];
  const int bh = blockIdx.y, n0 = blockIdx.x << 6;
  const int b = bh >> 3, h = bh & 7;
  const int t = threadIdx.x;
  const int row = t >> 2, d0 = (t & 3) << 4;
  const u16* src = qkvb + (size_t)(b * 2048 + n0 + row) * 1536 + 1024 + h * 64 + d0;
  *(uint4*)&tile[row][d0]     = *(const uint4*)src;
  *(uint4*)&tile[row][d0 + 8] = *(const uint4*)(src + 8);
  __syncthreads();
  const int dr = t >> 2, nn0 = (t & 3) << 4;
  u16* dst = vt + (size_t)(bh * 64 + dr) * 2048 + n0 + nn0;
  usv8 v0, v1;
  #pragma unroll
  for (int j = 0; j < 8; ++j) v0[j] = tile[nn0 + j][dr];
  #pragma unroll
  for (int j = 0; j < 8; ++j) v1[j] = tile[nn0 + 8 + j][dr];
  *(usv8*)dst = v0;
  *(usv8*)(dst + 8) = v1;
}

// ---------------- fused attention v2 (softmax over heads) ----------------
// grid (8 m-splits, 32 (b,n128)), 512 thr = 8 waves, 1 block/CU.
// Swapped QK^T (S^T: n = lane&15) -> in-lane head softmax -> cvt_pk +
// permlane re-layout -> PV, no P LDS round-trip. K dbuf via global_load_lds
// with pre-swizzled source; V dbuf reg-staged (issue-early/write-late).
__global__ __launch_bounds__(512, 2) void attn_kernel(
    const u16* __restrict__ qkvb, const u16* __restrict__ vt,
    float* __restrict__ accum)
{
  __shared__ u16 sK[2][8 * 32 * 64];   // [h][m][d], XOR ((m&7)<<4) within 128B rows
  __shared__ u16 sV[2][8 * 64 * 40];   // [h][d][m pad->40]
  const int tid = threadIdx.x;
  const int lane = tid & 63, w = tid >> 6;
  const int l15 = lane & 15, g = lane >> 4;
  const int b = blockIdx.y >> 4;
  const int n0 = (blockIdx.y & 15) << 7;
  const int mbase0 = blockIdx.x << 8;       // 256 m per block
  const float KSC = 0.125f * 1.4426950408889634f;  // scale * log2(e)

  // K staging: 32 segments of 1KB; wave w owns segments w*4+j.
  const u16* gK[4]; int ldsK[4];
  #pragma unroll
  for (int j = 0; j < 4; ++j) {
    const int seg = (w << 2) + j;
    const int kh = seg >> 2;
    const int mrow = ((seg & 3) << 3) + (lane >> 3);
    const int csw = ((lane & 7) ^ (mrow & 7)) << 3;   // pre-swizzled col (u16)
    gK[j] = qkvb + (size_t)(b * 2048 + mbase0 + mrow) * 1536 + 512 + kh * 64 + csw;
    ldsK[j] = seg << 9;
  }
  // V staging: thread -> 4 chunks of 16B; chunk i at V^T row i*128 + (tid>>2).
  const int t4 = tid >> 2, s4 = tid & 3;
  const u16* gV = vt + (size_t)(b * 512 + t4) * 2048 + mbase0 + (s4 << 3);
  const u16* qbase = qkvb + (size_t)(b * 2048 + n0 + (w << 4) + l15) * 1536;

  f32x4 acc[8][4] = {};
  uint4 va[4];

  // prologue: stage tile 0
  #pragma unroll
  for (int j = 0; j < 4; ++j) gload_lds16(gK[j], &sK[0][ldsK[j]]);
  #pragma unroll
  for (int i = 0; i < 4; ++i) va[i] = *(const uint4*)(gV + (size_t)i * 128 * 2048);
  #pragma unroll
  for (int i = 0; i < 4; ++i)
    *(uint4*)&sV[0][(i * 128 + t4) * 40 + (s4 << 3)] = va[i];
  __syncthreads();

  int buf = 0;
  for (int mt = 0; mt < 8; ++mt) {
    const int mb = mt << 5;
    if (mt < 7) {  // issue next-tile staging early
      #pragma unroll
      for (int j = 0; j < 4; ++j)
        gload_lds16(gK[j] + (size_t)(mb + 32) * 1536, &sK[buf ^ 1][ldsK[j]]);
      #pragma unroll
      for (int i = 0; i < 4; ++i)
        va[i] = *(const uint4*)(gV + (size_t)i * 128 * 2048 + mb + 32);
    }
    // ---- QK^T (A=K from LDS, B=Q from global/L1) -> S^T, n = l15 ----
    f32x4 sc[8][2];
    const u16* skb = &sK[buf][0];
    const int cx = (l15 & 7) << 4;
    #pragma unroll
    for (int h = 0; h < 8; ++h) {
      sv8 q0 = *(const sv8*)(qbase + h * 64 + (g << 3));
      sv8 q1 = *(const sv8*)(qbase + h * 64 + 32 + (g << 3));
      #pragma unroll
      for (int ms = 0; ms < 2; ++ms) {
        const char* rp = (const char*)skb + (((h << 5) + (ms << 4) + l15) << 7);
        sv8 k0 = *(const sv8*)(rp + (((g << 4)) ^ cx));
        sv8 k1 = *(const sv8*)(rp + ((64 + (g << 4)) ^ cx));
        f32x4 t = {0.0f, 0.0f, 0.0f, 0.0f};
        t = mfma16(k0, q0, t);
        t = mfma16(k1, q1, t);
        sc[h][ms] = t;
      }
    }
    // ---- softmax across 8 heads, fully in-lane ----
    #pragma unroll
    for (int ms = 0; ms < 2; ++ms)
      #pragma unroll
      for (int r = 0; r < 4; ++r) {
        float e[8]; float sum = 0.0f;
        #pragma unroll
        for (int h = 0; h < 8; ++h) { e[h] = exp2f(sc[h][ms][r] * KSC); sum += e[h]; }
        const float inv = __builtin_amdgcn_rcpf(sum);
        #pragma unroll
        for (int h = 0; h < 8; ++h) sc[h][ms][r] = e[h] * inv;
      }
    // ---- pack P to bf16 in-register, permlane re-layout, PV ----
    const u16* svb = &sV[buf][0];
    #pragma unroll
    for (int h = 0; h < 8; ++h) {
      u32 pa, pb, pc, pd;
      asm("v_cvt_pk_bf16_f32 %0, %1, %2" : "=v"(pa) : "v"(sc[h][0][0]), "v"(sc[h][0][1]));
      asm("v_cvt_pk_bf16_f32 %0, %1, %2" : "=v"(pc) : "v"(sc[h][0][2]), "v"(sc[h][0][3]));
      asm("v_cvt_pk_bf16_f32 %0, %1, %2" : "=v"(pb) : "v"(sc[h][1][0]), "v"(sc[h][1][1]));
      asm("v_cvt_pk_bf16_f32 %0, %1, %2" : "=v"(pd) : "v"(sc[h][1][2]), "v"(sc[h][1][3]));
      asm volatile("v_permlane32_swap_b32 %0, %1" : "+v"(pa), "+v"(pb));
      asm volatile("v_permlane16_swap_b32 %0, %1" : "+v"(pa), "+v"(pb));
      asm volatile("v_permlane32_swap_b32 %0, %1" : "+v"(pc), "+v"(pd));
      asm volatile("v_permlane16_swap_b32 %0, %1" : "+v"(pc), "+v"(pd));
      u32x4 pw; pw.x = pa; pw.y = pc; pw.z = pb; pw.w = pd;
      sv8 pf = __builtin_bit_cast(sv8, pw);
      #pragma unroll
      for (int dsub = 0; dsub < 4; ++dsub) {
        sv8 vf = *(const sv8*)(svb + h * 2560 + ((dsub << 4) + l15) * 40 + (g << 3));
        acc[h][dsub] = mfma16(pf, vf, acc[h][dsub]);
      }
    }
    if (mt < 7) {  // write-late V stage, one barrier per tile
      #pragma unroll
      for (int i = 0; i < 4; ++i)
        *(uint4*)&sV[buf ^ 1][(i * 128 + t4) * 40 + (s4 << 3)] = va[i];
      __syncthreads();
    }
    buf ^= 1;
  }
  // ---- combine m-splits: O rows n = n0 + w*16 + 4g + r ----
  float* ob = accum + ((size_t)(b * 2048 + n0 + (w << 4) + (g << 2)) << 9);
  #pragma unroll
  for (int h = 0; h < 8; ++h)
    #pragma unroll
    for (int dsub = 0; dsub < 4; ++dsub)
      #pragma unroll
      for (int r = 0; r < 4; ++r)
        atomicAdd(ob + (size_t)r * 512 + h * 64 + (dsub << 4) + l15,
                  acc[h][dsub][r]);
}

// ---------------- fp32 -> bf16 (attention accum -> proj input) ----------------
__global__ __launch_bounds__(256) void cast8(
    const float* __restrict__ in, u16* __restrict__ out)
{
  int i = blockIdx.x * 256 + threadIdx.x;  // 262144 total, 8 elems each
  float4 a = ((const float4*)in)[i * 2], b = ((const float4*)in)[i * 2 + 1];
  usv8 r;
  r[0] = f2bf(a.x); r[1] = f2bf(a.y); r[2] = f2bf(a.z); r[3] = f2bf(a.w);
  r[4] = f2bf(b.x); r[5] = f2bf(b.y); r[6] = f2bf(b.z); r[7] = f2bf(b.w);
  *(usv8*)(out + (size_t)i * 8) = r;
}

extern "C" void kernel_launch(void* const* d_in, const int* in_sizes, int n_in,
                              void* d_out, int out_size, void* d_ws, size_t ws_size,
                              hipStream_t stream) {
  const float* x      = (const float*)d_in[0];
  const float* ln_g   = (const float*)d_in[1];
  const float* ln_b   = (const float*)d_in[2];
  const float* qkv_w  = (const float*)d_in[3];
  const float* proj_w = (const float*)d_in[4];
  const float* proj_b = (const float*)d_in[5];
  const float* fc1_w  = (const float*)d_in[6];
  const float* fc1_b  = (const float*)d_in[7];
  const float* fc2_w  = (const float*)d_in[8];
  const float* fc2_b  = (const float*)d_in[9];
  char* ws = (char*)d_ws;
  u16*   w_qkv  = (u16*)(ws + 0);         // 1536x512 bf16
  u16*   w_proj = (u16*)(ws + 1572864);   // 512x512
  u16*   w_fc1  = (u16*)(ws + 2097152);   // 2048x512
  u16*   w_fc2  = (u16*)(ws + 4194304);   // 512x2048
  u16*   xn     = (u16*)(ws + 6291456);   // 4096x512 bf16 (LN out, reused)
  u16*   qkvb   = (u16*)(ws + 10485760);  // 4096x1536 bf16
  u16*   vtb    = (u16*)(ws + 23068672);  // [2][8][64][2048] bf16
  float* accum  = (float*)(ws + 27262976);// 4096x512 f32
  u16*   attnb  = (u16*)(ws + 35651584);  // 4096x512 bf16
  float* x1     = (float*)(ws + 39845888);// 4096x512 f32
  u16*   hbuf   = (u16*)(ws + 48234496);  // 4096x2048 bf16   (end: 62MB)

  hipMemsetAsync(accum, 0, (size_t)4096 * 512 * 4, stream);
  cast_w<<<3072, 256, 0, stream>>>(qkv_w, proj_w, fc1_w, fc2_w,
                                   w_qkv, w_proj, w_fc1, w_fc2);
  ln_kernel<<<1024, 256, 0, stream>>>(x, ln_g, ln_b, xn);
  gemm_kernel<0><<<dim3(32, 12), 256, 0, stream>>>(xn, w_qkv, 512, 1536,
                                                   nullptr, nullptr, qkvb);
  transpose_v<<<dim3(32, 16), 256, 0, stream>>>(qkvb, vtb);
  attn_kernel<<<dim3(8, 32), 512, 0, stream>>>(qkvb, vtb, accum);
  cast8<<<1024, 256, 0, stream>>>(accum, attnb);
  gemm_kernel<1><<<dim3(32, 4), 256, 0, stream>>>(attnb, w_proj, 512, 512,
                                                  proj_b, x, x1);
  ln_kernel<<<1024, 256, 0, stream>>>(x1, ln_g, ln_b, xn);
  gemm_kernel<2><<<dim3(32, 16), 256, 0, stream>>>(xn, w_fc1, 512, 2048,
                                                   fc1_b, nullptr, hbuf);
  gemm_kernel<1><<<dim3(32, 4), 256, 0, stream>>>(hbuf, w_fc2, 2048, 512,
                                                  fc2_b, x1, d_out);
}